// Round 8
// baseline (344.886 us; speedup 1.0000x reference)
//
#include <hip/hip_runtime.h>

// Correlation layer (FlowNet-style), max_displacement=4.
// in1,in2: [8,256,128,128] fp32 -> out: [8,81,128,128] fp32
// out[b, dy*9+dx, y, x] = sum_c in1[b,c,y,x] * in2[b,c,y+dy-4,x+dx-4] (0 if OOB)
//
// Round-8: r3 structure (best: 111us) + CHANNEL-SPLIT x2 for occupancy.
//   r3 was grid-capped at 2 blocks x 9 waves = 18 waves/CU with no pipe
//   saturated (VALU 40%, LDS-read ~46us/CU, dot2 ~35us/SIMD half-rate).
//   Split C=256 into 2 halves -> 1024 blocks -> 3 blocks/CU (LDS 155KB/160KB)
//   = 27 waves/CU; independent blocks overlap stage/compute phases.
//   Sum across the two c-half blocks: hipMemsetAsync(out,0) + f32 atomicAdd.
//   Swizzle: b = o&7 -> each XCD owns one batch; both c-halves of a (b,yp)
//   land on the same XCD -> L2-local atomics, in2 rows L2-hot across yp.

constexpr int Bn = 8, Cn = 256, Hn = 128, Wn = 128, HW = Hn * Wn;
constexpr int Dd = 4, ND = 9;
constexpr int CHB = 128;               // channels per block (half of Cn)
constexpr int KC = 16, NP = KC / 2;    // 8 f16x2 channel-pairs per chunk
constexpr int NT = 576;                // 9 waves: dy(9) x (2 rows x 32 quads)
constexpr int W2 = Wn + 8;             // padded in2 row width (136)

typedef __fp16 h2v __attribute__((ext_vector_type(2)));

static __device__ __forceinline__ unsigned packh2(float a, float b) {
  h2v h = __builtin_amdgcn_cvt_pkrtz(a, b);   // a->low, b->high
  return __builtin_bit_cast(unsigned, h);
}

static __device__ __forceinline__ float dot2(unsigned a, unsigned b, float c) {
#if __has_builtin(__builtin_amdgcn_fdot2)
  return __builtin_amdgcn_fdot2(__builtin_bit_cast(h2v, a),
                                __builtin_bit_cast(h2v, b), c, false);
#else
  h2v ha = __builtin_bit_cast(h2v, a), hb = __builtin_bit_cast(h2v, b);
  return c + (float)ha.x * (float)hb.x + (float)ha.y * (float)hb.y;
#endif
}

__global__ __launch_bounds__(NT) void corr_kernel(
    const float* __restrict__ in1, const float* __restrict__ in2,
    float* __restrict__ out)
{
  __shared__ __align__(16) unsigned s1h[NP][2][Wn];    // 8 KB
  __shared__ __align__(16) unsigned s2h[NP][10][W2];   // 43.5 KB

  // Decode: o%8 = XCD = batch; within XCD: 128 blocks = 64 y-pairs x 2 c-halves
  // (c-half is the fastest-varying bit after XCD -> both halves same XCD).
  const int o  = blockIdx.x;
  const int b  = o & 7;
  const int ch = (o >> 3) & 1;
  const int y0 = (o >> 4) << 1;

  const int tid  = threadIdx.x;
  const int dy   = tid >> 6;           // 0..8 (wave id)
  const int lane = tid & 63;
  const int row  = lane >> 5;          // 0..1
  const int x0   = (lane & 31) << 2;   // 4 consecutive px
  const int srow = dy + row;
  const size_t base = (size_t)b * Cn * HW + (size_t)ch * CHB * HW;

  // Zero s2h once: x-halo cols [0..3] and [132..135] (always zero) are
  // written ONLY here; interior + OOB rows are rewritten every chunk.
  for (int i = tid * 4; i < NP * 10 * W2; i += NT * 4)
    *(uint4*)(&s2h[0][0][0] + i) = uint4{0, 0, 0, 0};

  float4 acc[ND];
#pragma unroll
  for (int dx = 0; dx < ND; ++dx) acc[dx] = float4{0.f, 0.f, 0.f, 0.f};

  for (int c0 = 0; c0 < CHB; c0 += KC) {
    __syncthreads();                   // prev compute done (1st iter: zero-init)

    // ---- stage in1: NP*2*32 = 512 float4-groups ----
    for (int i = tid; i < NP * 2 * 32; i += NT) {
      const int p  = i >> 6;
      const int yy = (i >> 5) & 1;
      const int gx = (i & 31) << 2;
      const float* s = in1 + base + (size_t)(c0 + 2 * p) * HW + (y0 + yy) * Wn + gx;
      const float4 f0 = *(const float4*)s;
      const float4 f1 = *(const float4*)(s + HW);
      uint4 w;
      w.x = packh2(f0.x, f1.x); w.y = packh2(f0.y, f1.y);
      w.z = packh2(f0.z, f1.z); w.w = packh2(f0.w, f1.w);
      *(uint4*)&s1h[p][yy][gx] = w;
    }

    // ---- stage in2: NP*10*32 = 2560 float4-groups (interior cols only) ----
    for (int i = tid; i < NP * 10 * 32; i += NT) {
      const int p   = i / 320;
      const int rem = i - p * 320;
      const int r   = rem >> 5;
      const int gx  = (rem & 31) << 2;
      const int gy  = y0 + r - Dd;
      const bool ok = (unsigned)gy < (unsigned)Hn;
      const int gyc = ok ? gy : 0;
      const float* s = in2 + base + (size_t)(c0 + 2 * p) * HW + (size_t)gyc * Wn + gx;
      const float4 f0 = *(const float4*)s;
      const float4 f1 = *(const float4*)(s + HW);
      uint4 w;
      w.x = packh2(f0.x, f1.x); w.y = packh2(f0.y, f1.y);
      w.z = packh2(f0.z, f1.z); w.w = packh2(f0.w, f1.w);
      if (!ok) w = uint4{0, 0, 0, 0};
      *(uint4*)&s2h[p][r][4 + gx] = w;
    }
    __syncthreads();

    // ---- compute: per pair 4x ds_read_b128 -> 36 dot2 (72 MACs) ----
#pragma unroll
    for (int kc = 0; kc < NP; ++kc) {
      const unsigned* bp = &s2h[kc][srow][x0];
      const uint4 b0 = *(const uint4*)bp;
      const uint4 b1 = *(const uint4*)(bp + 4);
      const uint4 b2 = *(const uint4*)(bp + 8);
      const uint4 av = *(const uint4*)&s1h[kc][row][x0];
      const unsigned bb[12] = {b0.x, b0.y, b0.z, b0.w, b1.x, b1.y,
                               b1.z, b1.w, b2.x, b2.y, b2.z, b2.w};
      const unsigned aa[4] = {av.x, av.y, av.z, av.w};
#pragma unroll
      for (int dx = 0; dx < ND; ++dx) {
        acc[dx].x = dot2(aa[0], bb[dx + 0], acc[dx].x);
        acc[dx].y = dot2(aa[1], bb[dx + 1], acc[dx].y);
        acc[dx].z = dot2(aa[2], bb[dx + 2], acc[dx].z);
        acc[dx].w = dot2(aa[3], bb[dx + 3], acc[dx].w);
      }
    }
  }

  // ---- epilogue: f32 atomicAdd (two c-half blocks sum into each output) ----
#pragma unroll
  for (int dx = 0; dx < ND; ++dx) {
    const size_t oo =
        (((size_t)b * (ND * ND) + dy * ND + dx) * Hn + (y0 + row)) * Wn + x0;
    atomicAdd(&out[oo + 0], acc[dx].x);
    atomicAdd(&out[oo + 1], acc[dx].y);
    atomicAdd(&out[oo + 2], acc[dx].z);
    atomicAdd(&out[oo + 3], acc[dx].w);
  }
}

extern "C" void kernel_launch(void* const* d_in, const int* in_sizes, int n_in,
                              void* d_out, int out_size, void* d_ws, size_t ws_size,
                              hipStream_t stream) {
  const float* in1 = (const float*)d_in[0];
  const float* in2 = (const float*)d_in[1];
  float* out = (float*)d_out;
  hipMemsetAsync(d_out, 0, (size_t)out_size * sizeof(float), stream);
  dim3 grid(Bn * 2 * (Hn / 2));   // 1024 blocks: (xcd=batch | c-half | y-pair)
  dim3 block(NT);                 // 576 threads = 9 waves
  hipLaunchKernelGGL(corr_kernel, grid, block, 0, stream, in1, in2, out);
}

// Round 9
// 133.218 us; speedup vs baseline: 2.5889x; 2.5889x over previous
//
#include <hip/hip_runtime.h>

// Correlation layer (FlowNet-style), max_displacement=4.
// in1,in2: [8,256,128,128] fp32 -> out: [8,81,128,128] fp32
// out[b, dy*9+dx, y, x] = sum_c in1[b,c,y,x] * in2[b,c,y+dy-4,x+dx-4] (0 if OOB)
//
// Round-9: r6 structure repaired.
//  - 3-wave blocks (dy-triple): 1536 blocks -> 6 blocks/CU, 18 waves/CU;
//    six independent blocks overlap stage/compute phases (r3 had only 2).
//  - in2-only LDS (17.4 KB), f16x2 channel pairs, ds_read_b128 windows.
//  - in1 direct from global with a 1-pair PREFETCH ROTATE (r6 exposed the
//    load latency; r4 showed holding 3 staged tasks in regs kills occupancy —
//    8 in-flight VGPRs is the compromise).
//  - launch_bounds(192,5): VGPR cap 102 (r6's (192,7) strangled it to 36).
//  - hoisted staging descriptors (goff[6] + ok bitmask, no in-loop div/mod).

constexpr int Bn = 8, Cn = 256, Hn = 128, Wn = 128, HW = Hn * Wn;
constexpr int Dd = 4, ND = 9;
constexpr int KC = 16, NP = KC / 2;    // 8 f16x2 channel-pairs per chunk
constexpr int NCH = Cn / KC;           // 16 chunks
constexpr int NT = 192;                // 3 waves = one dy-group
constexpr int NR = 4;                  // staged in2 rows per block
constexpr int W2 = Wn + 8;             // staged row width (136 u32)
constexpr int NTASK = NP * NR * 32;    // 1024 staging quad-tasks per chunk

typedef __fp16 h2v __attribute__((ext_vector_type(2)));

static __device__ __forceinline__ unsigned packh2(float a, float b) {
  h2v h = __builtin_amdgcn_cvt_pkrtz(a, b);   // a->low, b->high
  return __builtin_bit_cast(unsigned, h);
}

static __device__ __forceinline__ float dot2(unsigned a, unsigned b, float c) {
#if __has_builtin(__builtin_amdgcn_fdot2)
  return __builtin_amdgcn_fdot2(__builtin_bit_cast(h2v, a),
                                __builtin_bit_cast(h2v, b), c, false);
#else
  h2v ha = __builtin_bit_cast(h2v, a), hb = __builtin_bit_cast(h2v, b);
  return c + (float)ha.x * (float)hb.x + (float)ha.y * (float)hb.y;
#endif
}

__global__ __launch_bounds__(NT, 5) void corr_kernel(
    const float* __restrict__ in1, const float* __restrict__ in2,
    float* __restrict__ out)
{
  __shared__ __align__(16) unsigned s2h[NP][NR][W2];   // 17.4 KB (in2 only)

  // XCD-chunked swizzle: 1536 blocks, bijective (1536 % 8 == 0);
  // 192 consecutive blocks (one batch) per XCD; dyg fastest -> L2-hot rows.
  int bid = blockIdx.x;
  bid = (bid & 7) * 192 + (bid >> 3);
  const int b   = bid / 192;
  int rem = bid - b * 192;
  const int yp  = rem / 3;
  const int dyg = rem - yp * 3;        // dy-group 0..2
  const int y0  = yp << 1;

  const int tid  = threadIdx.x;
  const int wv   = tid >> 6;           // wave 0..2
  const int dy   = dyg * 3 + wv;       // 0..8
  const int lane = tid & 63;
  const int row  = lane >> 5;          // 0..1
  const int x0   = (lane & 31) << 2;   // 4 consecutive px
  const int rr   = wv + row;           // staged in2 row index 0..3
  const size_t base = (size_t)b * Cn * HW;

  // ---- hoisted staging descriptors: 6 quad-tasks/thread ----
  // task t = tid + s*192: p = t>>7 (pair), r = (t>>5)&3 (row), q = t&31 (quad)
  unsigned goff[6];
  int okm = 0;
#pragma unroll
  for (int s = 0; s < 6; ++s) {
    const int t = tid + s * NT;
    if (t < NTASK) {
      const int p = t >> 7, r = (t >> 5) & 3, q = t & 31;
      const int gy = y0 + dyg * 3 + r - Dd;
      const bool ok = (unsigned)gy < (unsigned)Hn;
      goff[s] = (unsigned)((2 * p) * HW + (ok ? gy : 0) * Wn + (q << 2));
      okm |= (ok ? 1 : 0) << s;
    } else {
      goff[s] = 0;
    }
  }

  // ---- pre-zero x-halo quads (cols 0..3, 132..135): written only here ----
  for (int i = tid; i < NP * NR * 2; i += NT) {
    const int p = i >> 3, r = (i >> 1) & 3, side = i & 1;
    *(uint4*)&s2h[p][r][side ? 132 : 0] = uint4{0, 0, 0, 0};
  }

  float4 acc[ND];
#pragma unroll
  for (int dx = 0; dx < ND; ++dx) acc[dx] = float4{0.f, 0.f, 0.f, 0.f};

  const float* ip = in1 + base + (size_t)(y0 + row) * Wn + x0;

  for (int c = 0; c < NCH; ++c) {
    // ---- stage in2 chunk: 6 tasks (load float4 pair, pack, ds_write) ----
    const float* sp = in2 + base + (size_t)c * KC * HW;
#pragma unroll
    for (int s = 0; s < 6; ++s) {
      if (s == 5 && tid >= NTASK - 5 * NT) continue;  // wave-uniform tail
      const float* p0 = sp + goff[s];
      const float4 f0 = *(const float4*)p0;
      const float4 f1 = *(const float4*)(p0 + HW);
      uint4 w;
      w.x = packh2(f0.x, f1.x); w.y = packh2(f0.y, f1.y);
      w.z = packh2(f0.z, f1.z); w.w = packh2(f0.w, f1.w);
      if (!((okm >> s) & 1)) w = uint4{0, 0, 0, 0};
      const int t = tid + s * NT;
      const int p = t >> 7, r = (t >> 5) & 3, q = t & 31;
      *(uint4*)&s2h[p][r][(q << 2) + 4] = w;
    }

    // prefetch pair 0 of this chunk's in1 (latency hides under the barrier)
    const float* cp = ip + (size_t)c * KC * HW;
    float4 A0 = *(const float4*)cp;
    float4 A1 = *(const float4*)(cp + HW);
    __syncthreads();

    // ---- compute: per pair {pack A, prefetch next A, 3x ds_read_b128,
    //      36 dot2 (72 MAC)} ----
#pragma unroll
    for (int p = 0; p < NP; ++p) {
      const unsigned aa[4] = {packh2(A0.x, A1.x), packh2(A0.y, A1.y),
                              packh2(A0.z, A1.z), packh2(A0.w, A1.w)};
      if (p < NP - 1) {
        const float* np = cp + (size_t)(2 * p + 2) * HW;
        A0 = *(const float4*)np;
        A1 = *(const float4*)(np + HW);
      }
      const unsigned* bp = &s2h[p][rr][x0];
      const uint4 b0 = *(const uint4*)bp;
      const uint4 b1 = *(const uint4*)(bp + 4);
      const uint4 b2 = *(const uint4*)(bp + 8);
      const unsigned bb[12] = {b0.x, b0.y, b0.z, b0.w, b1.x, b1.y,
                               b1.z, b1.w, b2.x, b2.y, b2.z, b2.w};
#pragma unroll
      for (int dx = 0; dx < ND; ++dx) {
        acc[dx].x = dot2(aa[0], bb[dx + 0], acc[dx].x);
        acc[dx].y = dot2(aa[1], bb[dx + 1], acc[dx].y);
        acc[dx].z = dot2(aa[2], bb[dx + 2], acc[dx].z);
        acc[dx].w = dot2(aa[3], bb[dx + 3], acc[dx].w);
      }
    }
    __syncthreads();
  }

  // ---- epilogue: coalesced float4 stores ----
#pragma unroll
  for (int dx = 0; dx < ND; ++dx) {
    const size_t o =
        (((size_t)b * (ND * ND) + dy * ND + dx) * Hn + (y0 + row)) * Wn + x0;
    *(float4*)&out[o] = acc[dx];
  }
}

extern "C" void kernel_launch(void* const* d_in, const int* in_sizes, int n_in,
                              void* d_out, int out_size, void* d_ws, size_t ws_size,
                              hipStream_t stream) {
  const float* in1 = (const float*)d_in[0];
  const float* in2 = (const float*)d_in[1];
  float* out = (float*)d_out;
  dim3 grid(Bn * (Hn / 2) * 3);   // 1536 blocks: (batch, y-pair, dy-group)
  dim3 block(NT);                 // 192 threads = 3 waves (dy-triple)
  hipLaunchKernelGGL(corr_kernel, grid, block, 0, stream, in1, in2, out);
}

// Round 10
// 126.086 us; speedup vs baseline: 2.7353x; 1.0566x over previous
//
#include <hip/hip_runtime.h>

// Correlation layer (FlowNet-style), max_displacement=4.
// in1,in2: [8,256,128,128] fp32 -> out: [8,81,128,128] fp32
// out[b, dy*9+dx, y, x] = sum_c in1[b,c,y,x] * in2[b,c,y+dy-4,x+dx-4] (0 if OOB)
//
// Round-10: r3 shape + 2-phase double-buffered pipeline.
//  - in2-only LDS, KC=8, two 21.25 KB buffers (42.5 KB).
//  - per chunk: stage(c+1 -> other buf) ISSUED FIRST, then compute(c),
//    then ONE barrier. No stage->compute barrier: waves overlap phases.
//  - in1 not staged (all 9 waves share 2 rows -> L1 broadcast): global
//    dwordx4 + 1-pair prefetch rotate (8 regs, proven in r9).
//  - staging kept as r3's strip-mined loop (compiler keeps VGPR tight);
//    target VGPR <= 64 (>64 -> 16-wave class -> 1 block/CU, r4's failure).

constexpr int Bn = 8, Cn = 256, Hn = 128, Wn = 128, HW = Hn * Wn;
constexpr int Dd = 4, ND = 9;
constexpr int KC = 8, NP = KC / 2;     // 4 f16x2 channel-pairs per chunk
constexpr int NCH = Cn / KC;           // 32 chunks
constexpr int NT = 576;                // 9 waves: dy(9) x (2 rows x 32 quads)
constexpr int W2 = Wn + 8;             // padded in2 row width (136 u32)
constexpr int BUFSZ = NP * 10 * W2;    // 5440 u32 per buffer

typedef __fp16 h2v __attribute__((ext_vector_type(2)));

static __device__ __forceinline__ unsigned packh2(float a, float b) {
  h2v h = __builtin_amdgcn_cvt_pkrtz(a, b);   // a->low, b->high
  return __builtin_bit_cast(unsigned, h);
}

static __device__ __forceinline__ float dot2(unsigned a, unsigned b, float c) {
#if __has_builtin(__builtin_amdgcn_fdot2)
  return __builtin_amdgcn_fdot2(__builtin_bit_cast(h2v, a),
                                __builtin_bit_cast(h2v, b), c, false);
#else
  h2v ha = __builtin_bit_cast(h2v, a), hb = __builtin_bit_cast(h2v, b);
  return c + (float)ha.x * (float)hb.x + (float)ha.y * (float)hb.y;
#endif
}

__global__ __launch_bounds__(NT) void corr_kernel(
    const float* __restrict__ in1, const float* __restrict__ in2,
    float* __restrict__ out)
{
  __shared__ __align__(16) unsigned lds2[2 * BUFSZ];   // 42.5 KB

  // XCD-chunked swizzle: 512 blocks, 8 XCDs, bijective (512 % 8 == 0).
  int bid = blockIdx.x;
  bid = (bid & 7) * 64 + (bid >> 3);
  const int b  = bid >> 6;
  const int y0 = (bid & 63) << 1;

  const int tid  = threadIdx.x;
  const int dy   = tid >> 6;           // 0..8 (wave id)
  const int lane = tid & 63;
  const int row  = lane >> 5;          // 0..1
  const int x0   = (lane & 31) << 2;   // 4 consecutive px
  const int srow = dy + row;           // staged row 0..9
  const size_t base = (size_t)b * Cn * HW;

  // ---- zero x-halo quads of BOTH buffers (cols 0..3, 132..135): only here ----
  for (int i = tid; i < 2 * NP * 10 * 2; i += NT) {
    const int bf = i / (NP * 10 * 2), rem = i - bf * (NP * 10 * 2);
    const int pr = rem >> 1, side = rem & 1;
    *(uint4*)&lds2[bf * BUFSZ + pr * W2 + side * 132] = uint4{0, 0, 0, 0};
  }

  float4 acc[ND];
#pragma unroll
  for (int dx = 0; dx < ND; ++dx) acc[dx] = float4{0.f, 0.f, 0.f, 0.f};

  const float* ip = in1 + base + (size_t)(y0 + row) * Wn + x0;

  // ---- prologue: stage chunk 0 into buffer 0 ----
  for (int i = tid; i < NP * 10 * 32; i += NT) {
    const int p   = i / 320;
    const int rem = i - p * 320;
    const int r   = rem >> 5;
    const int gx  = (rem & 31) << 2;
    const int gy  = y0 + r - Dd;
    const bool ok = (unsigned)gy < (unsigned)Hn;
    const float* s = in2 + base + (size_t)(2 * p) * HW +
                     (size_t)(ok ? gy : 0) * Wn + gx;
    const float4 f0 = *(const float4*)s;
    const float4 f1 = *(const float4*)(s + HW);
    uint4 w;
    w.x = packh2(f0.x, f1.x); w.y = packh2(f0.y, f1.y);
    w.z = packh2(f0.z, f1.z); w.w = packh2(f0.w, f1.w);
    if (!ok) w = uint4{0, 0, 0, 0};
    *(uint4*)&lds2[(p * 10 + r) * W2 + 4 + gx] = w;
  }
  __syncthreads();

  for (int c = 0; c < NCH; ++c) {
    // ---- phase 1: issue staging of chunk c+1 into the other buffer ----
    if (c + 1 < NCH) {
      const unsigned nb = ((c + 1) & 1) * BUFSZ;
      const float* sp = in2 + base + (size_t)(c + 1) * KC * HW;
      for (int i = tid; i < NP * 10 * 32; i += NT) {
        const int p   = i / 320;
        const int rem = i - p * 320;
        const int r   = rem >> 5;
        const int gx  = (rem & 31) << 2;
        const int gy  = y0 + r - Dd;
        const bool ok = (unsigned)gy < (unsigned)Hn;
        const float* s = sp + (size_t)(2 * p) * HW +
                         (size_t)(ok ? gy : 0) * Wn + gx;
        const float4 f0 = *(const float4*)s;
        const float4 f1 = *(const float4*)(s + HW);
        uint4 w;
        w.x = packh2(f0.x, f1.x); w.y = packh2(f0.y, f1.y);
        w.z = packh2(f0.z, f1.z); w.w = packh2(f0.w, f1.w);
        if (!ok) w = uint4{0, 0, 0, 0};
        *(uint4*)&lds2[nb + (p * 10 + r) * W2 + 4 + gx] = w;
      }
    }

    // ---- phase 2: compute chunk c from current buffer ----
    const unsigned* bufp = &lds2[(c & 1) * BUFSZ];
    const float* cp = ip + (size_t)c * KC * HW;
    float4 A0 = *(const float4*)cp;
    float4 A1 = *(const float4*)(cp + HW);
#pragma unroll
    for (int p = 0; p < NP; ++p) {
      const unsigned aa[4] = {packh2(A0.x, A1.x), packh2(A0.y, A1.y),
                              packh2(A0.z, A1.z), packh2(A0.w, A1.w)};
      if (p < NP - 1) {
        const float* np = cp + (size_t)(2 * p + 2) * HW;
        A0 = *(const float4*)np;
        A1 = *(const float4*)(np + HW);
      }
      const unsigned* bp = bufp + (p * 10 + srow) * W2 + x0;
      const uint4 b0 = *(const uint4*)bp;
      const uint4 b1 = *(const uint4*)(bp + 4);
      const uint4 b2 = *(const uint4*)(bp + 8);
      const unsigned bb[12] = {b0.x, b0.y, b0.z, b0.w, b1.x, b1.y,
                               b1.z, b1.w, b2.x, b2.y, b2.z, b2.w};
#pragma unroll
      for (int dx = 0; dx < ND; ++dx) {
        acc[dx].x = dot2(aa[0], bb[dx + 0], acc[dx].x);
        acc[dx].y = dot2(aa[1], bb[dx + 1], acc[dx].y);
        acc[dx].z = dot2(aa[2], bb[dx + 2], acc[dx].z);
        acc[dx].w = dot2(aa[3], bb[dx + 3], acc[dx].w);
      }
    }
    __syncthreads();   // writes of buf^1 visible; reads of buf done
  }

  // ---- epilogue: coalesced float4 stores ----
#pragma unroll
  for (int dx = 0; dx < ND; ++dx) {
    const size_t o =
        (((size_t)b * (ND * ND) + dy * ND + dx) * Hn + (y0 + row)) * Wn + x0;
    *(float4*)&out[o] = acc[dx];
  }
}

extern "C" void kernel_launch(void* const* d_in, const int* in_sizes, int n_in,
                              void* d_out, int out_size, void* d_ws, size_t ws_size,
                              hipStream_t stream) {
  const float* in1 = (const float*)d_in[0];
  const float* in2 = (const float*)d_in[1];
  float* out = (float*)d_out;
  dim3 grid(Bn * (Hn / 2));   // 512 blocks: (batch, y-pair)
  dim3 block(NT);             // 576 threads = 9 waves
  hipLaunchKernelGGL(corr_kernel, grid, block, 0, stream, in1, in2, out);
}

// Round 11
// 109.931 us; speedup vs baseline: 3.1373x; 1.1470x over previous
//
#include <hip/hip_runtime.h>

// Correlation layer (FlowNet-style), max_displacement=4.
// in1,in2: [8,256,128,128] fp32 -> out: [8,81,128,128] fp32
// out[b, dy*9+dx, y, x] = sum_c in1[b,c,y,x] * in2[b,c,y+dy-4,x+dx-4] (0 if OOB)
//
// Round-11: r3 data flow (s1h+s2h both LDS, pack-once/broadcast) + r10's
// proven double-buffer skeleton. KC=8, buffer = 25.9 KB, x2 = 51.7 KB
// (same footprint as r3 -> 2 blocks/CU). Per chunk: stage(c+1 -> buf^1),
// compute(c <- buf), ONE barrier. VGPR must stay <= 64 (65+ -> 16-wave
// class -> 2nd block can't co-reside; r4's failure) -> strip-mined staging.

constexpr int Bn = 8, Cn = 256, Hn = 128, Wn = 128, HW = Hn * Wn;
constexpr int Dd = 4, ND = 9;
constexpr int KC = 8, NP = KC / 2;     // 4 f16x2 channel-pairs per chunk
constexpr int NCH = Cn / KC;           // 32 chunks
constexpr int NT = 576;                // 9 waves: dy(9) x (2 rows x 32 quads)
constexpr int W2 = Wn + 8;             // padded in2 row width (136 u32)
constexpr int S1 = NP * 2 * Wn;        // 1024 u32 (4 KB)
constexpr int S2 = NP * 10 * W2;       // 5440 u32 (21.75 KB)
constexpr int BUF = S1 + S2;           // 6464 u32
constexpr int NT1 = NP * 2 * 32;       // 256 in1 staging quad-tasks
constexpr int NT2 = NP * 10 * 32;      // 1280 in2 staging quad-tasks
constexpr int NTASK = NT1 + NT2;       // 1536

typedef __fp16 h2v __attribute__((ext_vector_type(2)));

static __device__ __forceinline__ unsigned packh2(float a, float b) {
  h2v h = __builtin_amdgcn_cvt_pkrtz(a, b);   // a->low, b->high
  return __builtin_bit_cast(unsigned, h);
}

static __device__ __forceinline__ float dot2(unsigned a, unsigned b, float c) {
#if __has_builtin(__builtin_amdgcn_fdot2)
  return __builtin_amdgcn_fdot2(__builtin_bit_cast(h2v, a),
                                __builtin_bit_cast(h2v, b), c, false);
#else
  h2v ha = __builtin_bit_cast(h2v, a), hb = __builtin_bit_cast(h2v, b);
  return c + (float)ha.x * (float)hb.x + (float)ha.y * (float)hb.y;
#endif
}

__global__ __launch_bounds__(NT) void corr_kernel(
    const float* __restrict__ in1, const float* __restrict__ in2,
    float* __restrict__ out)
{
  __shared__ __align__(16) unsigned lds[2 * BUF];   // 51.7 KB

  // XCD-chunked swizzle: 512 blocks, 8 XCDs, bijective (512 % 8 == 0).
  int bid = blockIdx.x;
  bid = (bid & 7) * 64 + (bid >> 3);
  const int b  = bid >> 6;
  const int y0 = (bid & 63) << 1;

  const int tid  = threadIdx.x;
  const int dy   = tid >> 6;           // 0..8 (wave id)
  const int lane = tid & 63;
  const int row  = lane >> 5;          // 0..1
  const int x0   = (lane & 31) << 2;   // 4 consecutive px
  const int srow = dy + row;           // staged in2 row 0..9
  const size_t base = (size_t)b * Cn * HW;

  // ---- zero x-halo quads of BOTH buffers (cols 0..3,132..135): only here ----
  for (int i = tid; i < 2 * NP * 10 * 2; i += NT) {
    const int bf = i / (NP * 10 * 2), rem = i - bf * (NP * 10 * 2);
    const int pr = rem >> 1, side = rem & 1;
    *(uint4*)&lds[bf * BUF + S1 + pr * W2 + side * 132] = uint4{0, 0, 0, 0};
  }

  float4 acc[ND];
#pragma unroll
  for (int dx = 0; dx < ND; ++dx) acc[dx] = float4{0.f, 0.f, 0.f, 0.f};

  // ---- staging routine (strip-mined: 2-3 tasks/thread, transient regs) ----
  auto stage = [&](int c, unsigned nb) {
    const float* p1 = in1 + base + (size_t)c * KC * HW;
    const float* p2 = in2 + base + (size_t)c * KC * HW;
    for (int i = tid; i < NTASK; i += NT) {
      uint4 w;
      int dst;
      if (i < NT1) {                   // in1: p(4) x row(2) x quad(32)
        const int p = i >> 6, yy = (i >> 5) & 1, gx = (i & 31) << 2;
        const float* s = p1 + (size_t)(2 * p) * HW + (y0 + yy) * Wn + gx;
        const float4 f0 = *(const float4*)s;
        const float4 f1 = *(const float4*)(s + HW);
        w.x = packh2(f0.x, f1.x); w.y = packh2(f0.y, f1.y);
        w.z = packh2(f0.z, f1.z); w.w = packh2(f0.w, f1.w);
        dst = nb + p * (2 * Wn) + yy * Wn + gx;
      } else {                         // in2: p(4) x row(10) x quad(32)
        const int g = i - NT1;
        const int p = g / 320, rem = g - p * 320;
        const int r = rem >> 5, gx = (rem & 31) << 2;
        const int gy = y0 + r - Dd;
        const bool ok = (unsigned)gy < (unsigned)Hn;
        const float* s = p2 + (size_t)(2 * p) * HW +
                         (size_t)(ok ? gy : 0) * Wn + gx;
        const float4 f0 = *(const float4*)s;
        const float4 f1 = *(const float4*)(s + HW);
        w.x = packh2(f0.x, f1.x); w.y = packh2(f0.y, f1.y);
        w.z = packh2(f0.z, f1.z); w.w = packh2(f0.w, f1.w);
        if (!ok) w = uint4{0, 0, 0, 0};
        dst = nb + S1 + (p * 10 + r) * W2 + 4 + gx;
      }
      *(uint4*)&lds[dst] = w;
    }
  };

  // ---- prologue: stage chunk 0 into buffer 0 ----
  stage(0, 0);
  __syncthreads();

  for (int c = 0; c < NCH; ++c) {
    // stage next chunk into the other buffer (no barrier before compute:
    // its global-load latency hides under this chunk's dot2 burst)
    if (c + 1 < NCH) stage(c + 1, ((c + 1) & 1) * BUF);

    // compute chunk c from current buffer
    const unsigned* bp0 = &lds[(c & 1) * BUF];
#pragma unroll
    for (int p = 0; p < NP; ++p) {
      const uint4 av = *(const uint4*)(bp0 + p * (2 * Wn) + row * Wn + x0);
      const unsigned* bp = bp0 + S1 + (p * 10 + srow) * W2 + x0;
      const uint4 b0 = *(const uint4*)bp;
      const uint4 b1 = *(const uint4*)(bp + 4);
      const uint4 b2 = *(const uint4*)(bp + 8);
      const unsigned aa[4]  = {av.x, av.y, av.z, av.w};
      const unsigned bb[12] = {b0.x, b0.y, b0.z, b0.w, b1.x, b1.y,
                               b1.z, b1.w, b2.x, b2.y, b2.z, b2.w};
#pragma unroll
      for (int dx = 0; dx < ND; ++dx) {
        acc[dx].x = dot2(aa[0], bb[dx + 0], acc[dx].x);
        acc[dx].y = dot2(aa[1], bb[dx + 1], acc[dx].y);
        acc[dx].z = dot2(aa[2], bb[dx + 2], acc[dx].z);
        acc[dx].w = dot2(aa[3], bb[dx + 3], acc[dx].w);
      }
    }
    __syncthreads();   // buf^1 writes visible; buf reads done
  }

  // ---- epilogue: coalesced float4 stores ----
#pragma unroll
  for (int dx = 0; dx < ND; ++dx) {
    const size_t o =
        (((size_t)b * (ND * ND) + dy * ND + dx) * Hn + (y0 + row)) * Wn + x0;
    *(float4*)&out[o] = acc[dx];
  }
}

extern "C" void kernel_launch(void* const* d_in, const int* in_sizes, int n_in,
                              void* d_out, int out_size, void* d_ws, size_t ws_size,
                              hipStream_t stream) {
  const float* in1 = (const float*)d_in[0];
  const float* in2 = (const float*)d_in[1];
  float* out = (float*)d_out;
  dim3 grid(Bn * (Hn / 2));   // 512 blocks: (batch, y-pair)
  dim3 block(NT);             // 576 threads = 9 waves
  hipLaunchKernelGGL(corr_kernel, grid, block, 0, stream, in1, in2, out);
}

// Round 12
// 97.192 us; speedup vs baseline: 3.5485x; 1.1311x over previous
//
#include <hip/hip_runtime.h>

// Correlation layer (FlowNet-style), max_displacement=4.
// in1,in2: [8,256,128,128] fp32 -> out: [8,81,128,128] fp32
// out[b, dy*9+dx, y, x] = sum_c in1[b,c,y,x] * in2[b,c,y+dy-4,x+dx-4] (0 if OOB)
//
// Round-12: r11 (dbuf pipeline, best 109.9us) + bank-conflict fix + hoisted
// staging descriptors.
//  - r11 surfaced 9.4M LDS bank-conflict cycles (~15us/CU): stage-writes
//    co-issue with compute-reads and the regions share bank alignment
//    (s1 pair stride 256u32 -> rotation 0). Pad: s1 pair stride 260 (rot 4),
//    s2 row width 140 (row rot 12, pair rot 24). All accesses stay 16B-aligned.
//  - staging descriptors (src ptr, dst, ok) hoisted once (r9-proven, ~10 VGPR);
//    per-chunk staging = +c*KCHW only.
//  - VGPR must stay <= 64 (65+ -> 16-wave class -> 1 block/CU, r4's failure).

constexpr int Bn = 8, Cn = 256, Hn = 128, Wn = 128, HW = Hn * Wn;
constexpr int Dd = 4, ND = 9;
constexpr int KC = 8, NP = KC / 2;     // 4 f16x2 channel-pairs per chunk
constexpr int NCH = Cn / KC;           // 32 chunks
constexpr int KCHW = KC * HW;
constexpr int NT = 576;                // 9 waves: dy(9) x (2 rows x 32 quads)
constexpr int S1P = 2 * Wn + 4;        // s1 pair stride 260 u32 (bank rot 4)
constexpr int W2  = Wn + 12;           // s2 row width 140 u32 (bank rot 12)
constexpr int S1  = NP * S1P;          // 1040 u32
constexpr int S2  = NP * 10 * W2;      // 5600 u32
constexpr int BUF = S1 + S2;           // 6640 u32 -> 2 buffers = 53.1 KB
constexpr int NT1 = NP * 2 * 32;       // 256 in1 staging quad-tasks
constexpr int NT2 = NP * 10 * 32;      // 1280 in2 staging quad-tasks
constexpr int NTASK = NT1 + NT2;       // 1536 (2.67 per thread)

typedef __fp16 h2v __attribute__((ext_vector_type(2)));

static __device__ __forceinline__ unsigned packh2(float a, float b) {
  h2v h = __builtin_amdgcn_cvt_pkrtz(a, b);   // a->low, b->high
  return __builtin_bit_cast(unsigned, h);
}

static __device__ __forceinline__ float dot2(unsigned a, unsigned b, float c) {
#if __has_builtin(__builtin_amdgcn_fdot2)
  return __builtin_amdgcn_fdot2(__builtin_bit_cast(h2v, a),
                                __builtin_bit_cast(h2v, b), c, false);
#else
  h2v ha = __builtin_bit_cast(h2v, a), hb = __builtin_bit_cast(h2v, b);
  return c + (float)ha.x * (float)hb.x + (float)ha.y * (float)hb.y;
#endif
}

__global__ __launch_bounds__(NT) void corr_kernel(
    const float* __restrict__ in1, const float* __restrict__ in2,
    float* __restrict__ out)
{
  __shared__ __align__(16) unsigned lds[2 * BUF];   // 53.1 KB

  // XCD-chunked swizzle: 512 blocks, 8 XCDs, bijective (512 % 8 == 0).
  int bid = blockIdx.x;
  bid = (bid & 7) * 64 + (bid >> 3);
  const int b  = bid >> 6;
  const int y0 = (bid & 63) << 1;

  const int tid  = threadIdx.x;
  const int dy   = tid >> 6;           // 0..8 (wave id)
  const int lane = tid & 63;
  const int row  = lane >> 5;          // 0..1
  const int x0   = (lane & 31) << 2;   // 4 consecutive px
  const int srow = dy + row;           // staged in2 row 0..9
  const size_t base = (size_t)b * Cn * HW;

  // ---- hoisted staging descriptors: up to 3 quad-tasks/thread ----
  const float* psrc[3];
  int  pdst[3];
  int  okm = 0;                        // bit s: in-bounds (write data vs zeros)
#pragma unroll
  for (int s = 0; s < 3; ++s) {
    const int t = tid + s * NT;
    if (t >= NTASK) { psrc[s] = in1; pdst[s] = 0; continue; }
    if (t < NT1) {                     // in1: p(4) x row(2) x quad(32)
      const int p = t >> 6, yy = (t >> 5) & 1, gx = (t & 31) << 2;
      psrc[s] = in1 + base + (size_t)(2 * p) * HW + (y0 + yy) * Wn + gx;
      pdst[s] = p * S1P + yy * Wn + gx;
      okm |= 1 << s;
    } else {                           // in2: p(4) x row(10) x quad(32)
      const int g = t - NT1;
      const int p = g / 320, rem = g - p * 320;
      const int r = rem >> 5, gx = (rem & 31) << 2;
      const int gy = y0 + r - Dd;
      const bool ok = (unsigned)gy < (unsigned)Hn;
      psrc[s] = in2 + base + (size_t)(2 * p) * HW +
                (size_t)(ok ? gy : 0) * Wn + gx;
      pdst[s] = S1 + (p * 10 + r) * W2 + 4 + gx;
      okm |= (ok ? 1 : 0) << s;
    }
  }

  // ---- zero x-halo quads of BOTH buffers (cols 0..3,132..135): only here ----
  for (int i = tid; i < 2 * NP * 10 * 2; i += NT) {
    const int bf = i / (NP * 10 * 2), rem = i - bf * (NP * 10 * 2);
    const int pr = rem >> 1, side = rem & 1;
    *(uint4*)&lds[bf * BUF + S1 + pr * W2 + side * 132] = uint4{0, 0, 0, 0};
  }

  float4 acc[ND];
#pragma unroll
  for (int dx = 0; dx < ND; ++dx) acc[dx] = float4{0.f, 0.f, 0.f, 0.f};

  // ---- prologue: stage chunk 0 into buffer 0 ----
#pragma unroll
  for (int s = 0; s < 3; ++s) {
    if (s == 2 && tid >= NTASK - 2 * NT) continue;   // wave-uniform tail
    const float4 f0 = *(const float4*)psrc[s];
    const float4 f1 = *(const float4*)(psrc[s] + HW);
    uint4 w;
    w.x = packh2(f0.x, f1.x); w.y = packh2(f0.y, f1.y);
    w.z = packh2(f0.z, f1.z); w.w = packh2(f0.w, f1.w);
    if (!((okm >> s) & 1)) w = uint4{0, 0, 0, 0};
    *(uint4*)&lds[pdst[s]] = w;
  }
  __syncthreads();

  for (int c = 0; c < NCH; ++c) {
    // ---- stage chunk c+1 into the other buffer (no barrier before compute:
    //      its global-load latency hides under this chunk's dot2 burst) ----
    if (c + 1 < NCH) {
      const unsigned nb = ((c + 1) & 1) * BUF;
      const size_t ofs = (size_t)(c + 1) * KCHW;
#pragma unroll
      for (int s = 0; s < 3; ++s) {
        if (s == 2 && tid >= NTASK - 2 * NT) continue;
        const float* sp = psrc[s] + ofs;
        const float4 f0 = *(const float4*)sp;
        const float4 f1 = *(const float4*)(sp + HW);
        uint4 w;
        w.x = packh2(f0.x, f1.x); w.y = packh2(f0.y, f1.y);
        w.z = packh2(f0.z, f1.z); w.w = packh2(f0.w, f1.w);
        if (!((okm >> s) & 1)) w = uint4{0, 0, 0, 0};
        *(uint4*)&lds[nb + pdst[s]] = w;
      }
    }

    // ---- compute chunk c from current buffer ----
    const unsigned* bp0 = &lds[(c & 1) * BUF];
#pragma unroll
    for (int p = 0; p < NP; ++p) {
      const uint4 av = *(const uint4*)(bp0 + p * S1P + row * Wn + x0);
      const unsigned* bp = bp0 + S1 + (p * 10 + srow) * W2 + x0;
      const uint4 b0 = *(const uint4*)bp;
      const uint4 b1 = *(const uint4*)(bp + 4);
      const uint4 b2 = *(const uint4*)(bp + 8);
      const unsigned aa[4]  = {av.x, av.y, av.z, av.w};
      const unsigned bb[12] = {b0.x, b0.y, b0.z, b0.w, b1.x, b1.y,
                               b1.z, b1.w, b2.x, b2.y, b2.z, b2.w};
#pragma unroll
      for (int dx = 0; dx < ND; ++dx) {
        acc[dx].x = dot2(aa[0], bb[dx + 0], acc[dx].x);
        acc[dx].y = dot2(aa[1], bb[dx + 1], acc[dx].y);
        acc[dx].z = dot2(aa[2], bb[dx + 2], acc[dx].z);
        acc[dx].w = dot2(aa[3], bb[dx + 3], acc[dx].w);
      }
    }
    __syncthreads();   // buf^1 writes visible; buf reads done
  }

  // ---- epilogue: coalesced float4 stores ----
#pragma unroll
  for (int dx = 0; dx < ND; ++dx) {
    const size_t o =
        (((size_t)b * (ND * ND) + dy * ND + dx) * Hn + (y0 + row)) * Wn + x0;
    *(float4*)&out[o] = acc[dx];
  }
}

extern "C" void kernel_launch(void* const* d_in, const int* in_sizes, int n_in,
                              void* d_out, int out_size, void* d_ws, size_t ws_size,
                              hipStream_t stream) {
  const float* in1 = (const float*)d_in[0];
  const float* in2 = (const float*)d_in[1];
  float* out = (float*)d_out;
  dim3 grid(Bn * (Hn / 2));   // 512 blocks: (batch, y-pair)
  dim3 block(NT);             // 576 threads = 9 waves
  hipLaunchKernelGGL(corr_kernel, grid, block, 0, stream, in1, in2, out);
}